// Round 9
// baseline (1672.218 us; speedup 1.0000x reference)
//
#include <hip/hip_runtime.h>
#include <math.h>

typedef __bf16 bf16x8 __attribute__((ext_vector_type(8)));
typedef float f32x4 __attribute__((ext_vector_type(4)));
typedef unsigned int u32x4 __attribute__((ext_vector_type(4)));
typedef unsigned long long u64;

constexpr int QQ = 1027;   // states
constexpr int SS = 26;     // alphabet
constexpr int TT = 512;    // sequence length
constexpr int NB = 256;    // batch
constexpr int KP = 1088;   // K padded (34 ksteps; 2 halves of 17)
constexpr int NP = 1040;   // N padded (65 tiles of 16)
constexpr int BTS = 1040;  // Bt row stride (floats)
constexpr int NSL = 13;    // N slices (5 tiles = 80 cols each)
constexpr int NBB = 16;    // batch blocks
constexpr int MB = 16;     // batch rows per block
constexpr int NWV = 10;    // waves: 5 col-tiles x 2 K-halves
constexpr int CBLK = NWV * 64;       // 640
constexpr int KH = 17;               // ksteps per K-half
constexpr int BUFN = NB * KP;        // bf16 elems per alpha buffer
constexpr int RQ = KP / 4;           // 272 u64 per alpha row
constexpr int LQ = RQ + 2;           // 274 u64 LDS row stride (2192B = 137 u32x4)
constexpr int TOTQ = MB * RQ;        // 4352 u64 per batch-block alpha
constexpr int NLD = TOTQ / CBLK;     // 6 full loads per thread
constexpr int NREM = TOTQ - NLD * CBLK;  // 512 threads do a 7th
constexpr int PSE = NBB * NSL * MB;  // 3328 tag-u64 per slot

__device__ __forceinline__ unsigned short f2bf(float f) {
  union { float f; unsigned u; } v; v.f = f;
  return (unsigned short)((v.u + 0x7fffu + ((v.u >> 16) & 1u)) >> 16);
}

__device__ __forceinline__ u64 ald8(const u64* p) {
  return __hip_atomic_load((u64*)p, __ATOMIC_RELAXED, __HIP_MEMORY_SCOPE_AGENT);
}
__device__ __forceinline__ void ast8(u64* p, u64 v) {
  __hip_atomic_store(p, v, __ATOMIC_RELAXED, __HIP_MEMORY_SCOPE_AGENT);
}

// Spin until the (s5|tag) word carries tag==texp; returns s5.
__device__ __forceinline__ float spin_tag(const u64* p, unsigned texp) {
  u64 v = ald8(p);
  while ((unsigned)(v >> 32) != texp) {
    __builtin_amdgcn_s_sleep(1);
    v = ald8(p);
  }
  union { unsigned u; float f; } w; w.u = (unsigned)v;
  return w.f;
}

__global__ void k_zero(u32x4* p, int n) {
  int i = blockIdx.x * blockDim.x + threadIdx.x;
  if (i < n) p[i] = (u32x4){0u, 0u, 0u, 0u};
}

__global__ void k_prep_init(const float* __restrict__ il, float* __restrict__ ip) {
  __shared__ float red[1024];
  int tid = threadIdx.x;
  float m = -1e30f;
  for (int q = tid; q < QQ; q += 1024) m = fmaxf(m, il[q]);
  red[tid] = m; __syncthreads();
  for (int off = 512; off > 0; off >>= 1) {
    if (tid < off) red[tid] = fmaxf(red[tid], red[tid + off]);
    __syncthreads();
  }
  m = red[0]; __syncthreads();
  float s = 0.f;
  for (int q = tid; q < QQ; q += 1024) s += expf(il[q] - m);
  red[tid] = s; __syncthreads();
  for (int off = 512; off > 0; off >>= 1) {
    if (tid < off) red[tid] += red[tid + off];
    __syncthreads();
  }
  s = red[0];
  float inv = 1.0f / s;
  for (int q = tid; q < QQ; q += 1024) ip[q] = expf(il[q] - m) * inv;
}

__global__ void k_prep_B(const float* __restrict__ bl, float* __restrict__ bt) {
  int q = blockIdx.x * blockDim.x + threadIdx.x;
  if (q >= QQ) return;
  const float* row = bl + (size_t)q * SS;
  float m = -1e30f;
  for (int c = 0; c < SS; ++c) m = fmaxf(m, row[c]);
  float s = 0.f;
  for (int c = 0; c < SS; ++c) s += expf(row[c] - m);
  float inv = 1.0f / s;
  for (int c = 0; c < SS; ++c) bt[c * BTS + q] = expf(row[c] - m) * inv;
}

// Row r of A -> column r of A^T[n][k] (bf16)
__global__ void k_prep_A(const float* __restrict__ al, unsigned short* __restrict__ at) {
  int r = blockIdx.x;
  const float* row = al + (size_t)r * QQ;
  __shared__ float red[256];
  int tid = threadIdx.x;
  float m = -1e30f;
  for (int n = tid; n < QQ; n += 256) m = fmaxf(m, row[n]);
  red[tid] = m; __syncthreads();
  for (int off = 128; off > 0; off >>= 1) {
    if (tid < off) red[tid] = fmaxf(red[tid], red[tid + off]);
    __syncthreads();
  }
  m = red[0]; __syncthreads();
  float s = 0.f;
  for (int n = tid; n < QQ; n += 256) s += expf(row[n] - m);
  red[tid] = s; __syncthreads();
  for (int off = 128; off > 0; off >>= 1) {
    if (tid < off) red[tid] += red[tid + off];
    __syncthreads();
  }
  s = red[0];
  float inv = 1.0f / s;
  for (int n = tid; n < QQ; n += 256) at[(size_t)n * KP + r] = f2bf(expf(row[n] - m) * inv);
}

// f0 = init * E[:,0] (unnormalized) into buf0 + tagged per-slice row-sums (tag=0)
__global__ void k_init_step(const int* __restrict__ seq, const float* __restrict__ ip,
                            const float* __restrict__ Bt, unsigned short* __restrict__ buf0,
                            u64* __restrict__ psumE) {
  int b = blockIdx.x, tid = threadIdx.x;
  __shared__ float sp[16];
  if (tid < 16) sp[tid] = 0.f;
  __syncthreads();
  int c0 = seq[b * TT];
  for (int q = tid; q < NP; q += 256) {
    float v = ip[q] * Bt[c0 * BTS + q];   // ip[q>=QQ]=0, Bt[.,q>=QQ]=0
    buf0[(size_t)b * KP + q] = f2bf(v);
    atomicAdd(&sp[q / 80], v);
  }
  __syncthreads();
  if (tid < NSL) {
    union { float f; unsigned u; } w; w.f = sp[tid];
    psumE[(size_t)(b / MB) * (NSL * MB) + tid * MB + (b % MB)] = (u64)w.u;  // tag 0
  }
}

__global__ __launch_bounds__(CBLK, 1) void k_hmm_coop(
    const int* __restrict__ seq, const unsigned short* __restrict__ At,
    const float* __restrict__ Bt, unsigned short* __restrict__ bufB,
    u64* __restrict__ psumE, float* __restrict__ out) {
  __shared__ u64 aldsq[MB * LQ];          // 35 KB: this block's alpha (bf16)
  __shared__ f32x4 accred[5][64];         // 5 KB: K-half partial handoff
  __shared__ float srow[MB][NSL + 1];     // per-row per-slice scale partials
  __shared__ float inv_lds[MB];
  __shared__ float spart[MB][5];

  const int tid = threadIdx.x, wg = blockIdx.x;
  const int bb = wg % NBB, sl = wg / NBB; // 13 slice-WGs per batch block
  const int lane = tid & 63, wv = tid >> 6;
  const int p = wv >> 1, h = wv & 1;      // col-tile 0..4, K-half 0..1
  const int lrow = lane >> 4, lcol = lane & 15;
  const int n0w = (sl * 5 + p) * 16;      // this wave's 16-col tile base
  const int ssl = tid >> 4, srw = tid & 15;  // spinner: slice, row

  // --- step-invariant At fragments for this wave's K-half (68 VGPRs)
  u32x4 atr[KH];
  {
    const u32x4* atp =
        (const u32x4*)(At + (size_t)(n0w + lcol) * KP + 8 * lrow) + (size_t)h * KH * 4;
#pragma unroll
    for (int j = 0; j < KH; ++j) atr[j] = atp[4 * j];
#pragma unroll
    for (int j = 0; j < KH; ++j) asm volatile("" : "+v"(atr[j]));
  }

  float ll = 0.f;

  for (int t = 1; t < TT; ++t) {
    const int rd = (t - 1) % 3, wri = t % 3;
    const unsigned texp = (unsigned)(t - 1);
    const u64* tagb = psumE + ((size_t)rd * NBB + bb) * (NSL * MB);
    u64* tagw = psumE + ((size_t)wri * NBB + bb) * (NSL * MB);
    const u64* ain = (const u64*)(bufB + (size_t)rd * BUFN) + (size_t)bb * TOTQ;
    u64* wbuf8 = (u64*)(bufB + (size_t)wri * BUFN);

    // off-critical-path: emission quad for h=0 epilogue waves
    f32x4 ev;
    if (h == 0) {
      const int ch = seq[(bb * MB + lcol) * TT + t];
      ev = *(const f32x4*)(Bt + (size_t)ch * BTS + n0w + 4 * lrow);
    }

    // --- parallel spin: 208 threads watch one (slice,row) tag each
    if (tid < NSL * MB) srow[srw][ssl] = spin_tag(tagb + ssl * MB + srw, texp);
    __syncthreads();  // sync1: all tags seen -> alpha readable at L3

    // --- bulk alpha loads, full MLP
    u64 av[NLD], avx = 0;
    const u64* asrc = ain + tid;
#pragma unroll
    for (int j = 0; j < NLD; ++j) av[j] = ald8(asrc + j * CBLK);
    if (tid < NREM) avx = ald8(asrc + NLD * CBLK);

    // --- stage into LDS
#pragma unroll
    for (int j = 0; j < NLD; ++j) {
      int g = tid + j * CBLK;
      int r = g / RQ;
      aldsq[r * LQ + (g - r * RQ)] = av[j];
    }
    if (tid < NREM) {
      int g = tid + NLD * CBLK;
      int r = g / RQ;
      aldsq[r * LQ + (g - r * RQ)] = avx;
    }
    // --- scales + log-lik (overlapped with other threads' staging)
    if (tid < MB) {
      float s = 0.f;
#pragma unroll
      for (int c = 0; c < NSL; ++c) s += srow[tid][c];
      ll += logf(s);
      inv_lds[tid] = 1.0f / s;
    }
    __syncthreads();  // sync2: LDS alpha + inv ready

    // --- k-loop: 17 x (ds_read + MFMA), At resident in regs
    // row stride in u32x4 units = LQ*8/16 = LQ/2 = 137
    const u32x4* ap =
        ((const u32x4*)aldsq) + lcol * (LQ / 2) + lrow + (size_t)h * KH * 4;
    f32x4 acc = (f32x4){0.f, 0.f, 0.f, 0.f};
#pragma unroll
    for (int j = 0; j < KH; ++j) {
      u32x4 af = ap[4 * j];
      acc = __builtin_amdgcn_mfma_f32_16x16x32_bf16(
          __builtin_bit_cast(bf16x8, atr[j]), __builtin_bit_cast(bf16x8, af),
          acc, 0, 0, 0);
    }

    // --- K-half reduction handoff
    if (h == 1) accred[p][lane] = acc;
    __syncthreads();  // sync3

    if (h == 0) {
      const f32x4 other = accred[p][lane];
      const float inv = inv_lds[lcol];
      float rs = 0.f;
      u64 hv = 0;
#pragma unroll
      for (int i = 0; i < 4; ++i) {
        float v = (acc[i] + other[i]) * ev[i] * inv;
        rs += v;
        hv |= (u64)f2bf(v) << (16 * i);
      }
      ast8(wbuf8 + (size_t)(bb * MB + lcol) * RQ + (n0w >> 2) + lrow, hv);
      rs += __shfl_xor(rs, 16);
      rs += __shfl_xor(rs, 32);
      if (lane < 16) spart[lane][p] = rs;
    }
    asm volatile("s_waitcnt vmcnt(0)" ::: "memory");  // own alpha stores L3-acked
    __syncthreads();  // sync4: all stores drained + spart visible

    // --- publish (s5 | tag): the store IS the arrival signal
    if (tid < MB) {
      float s5 = spart[tid][0] + spart[tid][1] + spart[tid][2] +
                 spart[tid][3] + spart[tid][4];
      union { float f; unsigned u; } w; w.f = s5;
      ast8(tagw + sl * MB + tid, (u64)w.u | ((u64)(unsigned)t << 32));
    }
  }

  // --- final scale (tag TT-1) + output
  if (sl == 0) {
    const u64* tb = psumE + ((size_t)((TT - 1) % 3) * NBB + bb) * (NSL * MB);
    if (tid < NSL * MB)
      srow[srw][ssl] = spin_tag(tb + ssl * MB + srw, (unsigned)(TT - 1));
    __syncthreads();
    if (tid < MB) {
      float s = 0.f;
#pragma unroll
      for (int c = 0; c < NSL; ++c) s += srow[tid][c];
      out[bb * MB + tid] = ll + logf(s);
    }
  }
}

extern "C" void kernel_launch(void* const* d_in, const int* in_sizes, int n_in,
                              void* d_out, int out_size, void* d_ws, size_t ws_size,
                              hipStream_t stream) {
  const int* seq = (const int*)d_in[0];
  const float* Al = (const float*)d_in[1];
  const float* Bl = (const float*)d_in[2];
  const float* il = (const float*)d_in[3];
  float* out = (float*)d_out;

  char* ws = (char*)d_ws;
  unsigned short* At = (unsigned short*)ws;               // 1040*1088*2 = 2,263,040
  size_t off_bt = (size_t)NP * KP * 2;
  float* Bt = (float*)(ws + off_bt);                      // 26*1040*4 = 108,160
  size_t off_ip = off_bt + (size_t)SS * BTS * 4;
  float* ip = (float*)(ws + off_ip);                      // 1040*4
  size_t off_buf = off_ip + (size_t)NP * 4;
  unsigned short* bufB = (unsigned short*)(ws + off_buf); // 3*256*1088*2 = 1,671,168
  size_t off_ps = off_buf + (size_t)3 * BUFN * 2;
  u64* psumE = (u64*)(ws + off_ps);                       // 3*3328*8 = 79,872
  size_t total = off_ps + (size_t)3 * PSE * 8;
  int n16 = (int)((total + 15) / 16);

  k_zero<<<(n16 + 255) / 256, 256, 0, stream>>>((u32x4*)ws, n16);
  k_prep_init<<<1, 1024, 0, stream>>>(il, ip);
  k_prep_B<<<(QQ + 255) / 256, 256, 0, stream>>>(Bl, Bt);
  k_prep_A<<<QQ, 256, 0, stream>>>(Al, At);
  k_init_step<<<NB, 256, 0, stream>>>(seq, ip, Bt, bufB, psumE);

  void* args[] = {(void*)&seq, (void*)&At, (void*)&Bt, (void*)&bufB,
                  (void*)&psumE, (void*)&out};
  hipLaunchCooperativeKernel((void*)k_hmm_coop, dim3(NBB * NSL), dim3(CBLK),
                             args, 0, stream);
}

// Round 10
// 1624.843 us; speedup vs baseline: 1.0292x; 1.0292x over previous
//
#include <hip/hip_runtime.h>
#include <math.h>

typedef __bf16 bf16x8 __attribute__((ext_vector_type(8)));
typedef float f32x4 __attribute__((ext_vector_type(4)));
typedef unsigned int u32x4 __attribute__((ext_vector_type(4)));
typedef unsigned long long u64;

constexpr int QQ = 1027;   // states
constexpr int SS = 26;     // alphabet
constexpr int TT = 512;    // sequence length
constexpr int NB = 256;    // batch
constexpr int KP = 1056;   // K padded (33 ksteps)
constexpr int NP = 1040;   // N padded (65 tiles of 16)
constexpr int BTS = 1040;  // Bt row stride (floats)
constexpr int NSL = 13;    // N slices (5 tiles = 80 cols each)
constexpr int NBB = 16;    // batch blocks
constexpr int MB = 16;     // batch rows per block
constexpr int NWV = 5;     // waves per WG (1 col-tile each)
constexpr int CBLK = NWV * 64;       // 320
constexpr int KSTEPS = KP / 32;      // 33
constexpr int BUFN = NB * KP;        // bf16 elems per alpha buffer
constexpr int RQ = KP / 4;           // 264 u64 per alpha row
constexpr int LQ = 274;              // u64 LDS row stride: 548 dwords = 4 mod 32 (bank-clean)
constexpr int TOTQ = MB * RQ;        // 4224 u64 per batch-block alpha
constexpr int NLD = TOTQ / CBLK;     // 13 full loads per thread
constexpr int NREM = TOTQ - NLD * CBLK;  // 64 threads do a 14th
constexpr int NTAG = NSL * NWV;      // 65 arrival tags per batch block
constexpr int TSTR = 80;             // tag row stride (padded)

__device__ __forceinline__ unsigned short f2bf(float f) {
  union { float f; unsigned u; } v; v.f = f;
  return (unsigned short)((v.u + 0x7fffu + ((v.u >> 16) & 1u)) >> 16);
}

__device__ __forceinline__ u64 ald8(const u64* p) {
  return __hip_atomic_load((u64*)p, __ATOMIC_RELAXED, __HIP_MEMORY_SCOPE_AGENT);
}
__device__ __forceinline__ void ast8(u64* p, u64 v) {
  __hip_atomic_store(p, v, __ATOMIC_RELAXED, __HIP_MEMORY_SCOPE_AGENT);
}

// Spin until the tag word carries tag==texp (payload-free arrival flag).
__device__ __forceinline__ void spin_tag(const u64* p, unsigned texp) {
  u64 v = ald8(p);
  while ((unsigned)(v >> 32) != texp) {
    __builtin_amdgcn_s_sleep(1);
    v = ald8(p);
  }
}

__device__ __forceinline__ float sum4bf(u64 q) {
  union { unsigned u; float f; } a, b, c, d;
  a.u = ((unsigned)(q & 0xFFFFu)) << 16;
  b.u = (unsigned)(q >> 16) << 16;   // truncates high bits via <<16? no: mask below
  b.u = ((unsigned)((q >> 16) & 0xFFFFu)) << 16;
  c.u = ((unsigned)((q >> 32) & 0xFFFFu)) << 16;
  d.u = ((unsigned)((q >> 48) & 0xFFFFu)) << 16;
  return (a.f + b.f) + (c.f + d.f);
}

__global__ void k_zero(u32x4* p, int n) {
  int i = blockIdx.x * blockDim.x + threadIdx.x;
  if (i < n) p[i] = (u32x4){0u, 0u, 0u, 0u};
}

__global__ void k_prep_init(const float* __restrict__ il, float* __restrict__ ip) {
  __shared__ float red[1024];
  int tid = threadIdx.x;
  float m = -1e30f;
  for (int q = tid; q < QQ; q += 1024) m = fmaxf(m, il[q]);
  red[tid] = m; __syncthreads();
  for (int off = 512; off > 0; off >>= 1) {
    if (tid < off) red[tid] = fmaxf(red[tid], red[tid + off]);
    __syncthreads();
  }
  m = red[0]; __syncthreads();
  float s = 0.f;
  for (int q = tid; q < QQ; q += 1024) s += expf(il[q] - m);
  red[tid] = s; __syncthreads();
  for (int off = 512; off > 0; off >>= 1) {
    if (tid < off) red[tid] += red[tid + off];
    __syncthreads();
  }
  s = red[0];
  float inv = 1.0f / s;
  for (int q = tid; q < QQ; q += 1024) ip[q] = expf(il[q] - m) * inv;
}

__global__ void k_prep_B(const float* __restrict__ bl, float* __restrict__ bt) {
  int q = blockIdx.x * blockDim.x + threadIdx.x;
  if (q >= QQ) return;
  const float* row = bl + (size_t)q * SS;
  float m = -1e30f;
  for (int c = 0; c < SS; ++c) m = fmaxf(m, row[c]);
  float s = 0.f;
  for (int c = 0; c < SS; ++c) s += expf(row[c] - m);
  float inv = 1.0f / s;
  for (int c = 0; c < SS; ++c) bt[c * BTS + q] = expf(row[c] - m) * inv;
}

// Row r of A -> column r of A^T[n][k] (bf16)
__global__ void k_prep_A(const float* __restrict__ al, unsigned short* __restrict__ at) {
  int r = blockIdx.x;
  const float* row = al + (size_t)r * QQ;
  __shared__ float red[256];
  int tid = threadIdx.x;
  float m = -1e30f;
  for (int n = tid; n < QQ; n += 256) m = fmaxf(m, row[n]);
  red[tid] = m; __syncthreads();
  for (int off = 128; off > 0; off >>= 1) {
    if (tid < off) red[tid] = fmaxf(red[tid], red[tid + off]);
    __syncthreads();
  }
  m = red[0]; __syncthreads();
  float s = 0.f;
  for (int n = tid; n < QQ; n += 256) s += expf(row[n] - m);
  red[tid] = s; __syncthreads();
  for (int off = 128; off > 0; off >>= 1) {
    if (tid < off) red[tid] += red[tid + off];
    __syncthreads();
  }
  s = red[0];
  float inv = 1.0f / s;
  for (int n = tid; n < QQ; n += 256) at[(size_t)n * KP + r] = f2bf(expf(row[n] - m) * inv);
}

// f0 = init * E[:,0] (unnormalized) into buf0. Tags slot0 stay 0 (= texp for t=1).
__global__ void k_init_step(const int* __restrict__ seq, const float* __restrict__ ip,
                            const float* __restrict__ Bt, unsigned short* __restrict__ buf0) {
  int b = blockIdx.x, tid = threadIdx.x;
  int c0 = seq[b * TT];
  for (int q = tid; q < NP; q += 256)
    buf0[(size_t)b * KP + q] = f2bf(ip[q] * Bt[c0 * BTS + q]);
}

__global__ __launch_bounds__(CBLK, 1) void k_hmm_coop(
    const int* __restrict__ seq, const unsigned short* __restrict__ At,
    const float* __restrict__ Bt, unsigned short* __restrict__ bufB,
    u64* __restrict__ tagsE, float* __restrict__ out) {
  __shared__ u64 aldsq[MB * LQ];          // ~35 KB: this block's alpha (bf16)
  __shared__ float srowF[MB];             // final-step row sums only

  const int tid = threadIdx.x, wg = blockIdx.x;
  const int bb = wg % NBB, sl = wg / NBB; // 13 slice-WGs per batch block
  const int lane = tid & 63, wv = tid >> 6;
  const int lrow = lane >> 4, lcol = lane & 15;
  const int n0w = (sl * NWV + wv) * 16;   // this wave's 16-col tile base

  // step-invariant At fragments (compiler may place in AGPRs — unified file)
  u32x4 atr[KSTEPS];
  {
    const u32x4* atp = (const u32x4*)(At + (size_t)(n0w + lcol) * KP + 8 * lrow);
#pragma unroll
    for (int ks = 0; ks < KSTEPS; ++ks) atr[ks] = atp[4 * ks];
  }
  const u32x4 ones4 = (u32x4){0x3F803F80u, 0x3F803F80u, 0x3F803F80u, 0x3F803F80u};

  float ll = 0.f;

  for (int t = 1; t < TT; ++t) {
    const int rd = (t - 1) % 3, wri = t % 3;
    const unsigned texp = (unsigned)(t - 1);
    const u64* tagb = tagsE + ((size_t)rd * NBB + bb) * TSTR;
    u64* tagw = tagsE + ((size_t)wri * NBB + bb) * TSTR;
    const u64* ain = (const u64*)(bufB + (size_t)rd * BUFN) + (size_t)bb * TOTQ;
    u64* wbuf8 = (u64*)(bufB + (size_t)wri * BUFN);

    // off-critical-path: emission quad (L2-resident, no exchange dependency)
    const int ch = seq[(bb * MB + lcol) * TT + t];
    const f32x4 ev = *(const f32x4*)(Bt + (size_t)ch * BTS + n0w + 4 * lrow);

    // --- parallel spin: 65 threads watch one producer-wave tag each
    if (tid < NTAG) spin_tag(tagb + tid, texp);
    __syncthreads();  // sync1: all chunks arrived at L3

    // --- bulk alpha loads, coalesced, full MLP
    u64 av[NLD], avx = 0;
    const u64* asrc = ain + tid;
#pragma unroll
    for (int j = 0; j < NLD; ++j) av[j] = ald8(asrc + j * CBLK);
    if (tid < NREM) avx = ald8(asrc + NLD * CBLK);

    // --- stage into LDS
#pragma unroll
    for (int j = 0; j < NLD; ++j) {
      int g = tid + j * CBLK;
      int r = g / RQ;
      aldsq[r * LQ + (g - r * RQ)] = av[j];
    }
    if (tid < NREM) {
      int g = tid + NLD * CBLK;
      int r = g / RQ;
      aldsq[r * LQ + (g - r * RQ)] = avx;
    }
    __syncthreads();  // sync2: LDS alpha ready

    // --- k-loop: each ds_read feeds TWO MFMAs: the GEMM and the ones-row-sum
    const u32x4* ap = ((const u32x4*)aldsq) + lcol * (LQ / 2) + lrow;
    f32x4 acc = (f32x4){0.f, 0.f, 0.f, 0.f};
    f32x4 accs = (f32x4){0.f, 0.f, 0.f, 0.f};
#pragma unroll
    for (int ks = 0; ks < KSTEPS; ++ks) {
      u32x4 af = ap[4 * ks];
      acc = __builtin_amdgcn_mfma_f32_16x16x32_bf16(
          __builtin_bit_cast(bf16x8, atr[ks]), __builtin_bit_cast(bf16x8, af),
          acc, 0, 0, 0);
      accs = __builtin_amdgcn_mfma_f32_16x16x32_bf16(
          __builtin_bit_cast(bf16x8, ones4), __builtin_bit_cast(bf16x8, af),
          accs, 0, 0, 0);
    }

    // --- epilogue: s materialized in-register; no cross-lane, no cross-wave
    const float s = accs[0];              // = sum_k f[lcol][k]  (all 4 entries equal)
    const float inv = 1.0f / s;
    if (sl == 0 && wv == 0) ll += logf(s);

    u64 hv = 0;
#pragma unroll
    for (int i = 0; i < 4; ++i) {
      float v = acc[i] * ev[i] * inv;
      hv |= (u64)f2bf(v) << (16 * i);
    }
    ast8(wbuf8 + (size_t)(bb * MB + lcol) * RQ + (n0w >> 2) + lrow, hv);
    asm volatile("s_waitcnt vmcnt(0)" ::: "memory");  // own 16x16 chunk acked at L3
    if (lane == 0) ast8(tagw + sl * NWV + wv, (u64)(unsigned)t << 32);  // per-wave publish
  }

  // --- final: sl==0 WGs sum alpha_{T-1} and write out
  if (sl == 0) {
    if (tid < MB) srowF[tid] = 0.f;
    const int fs = (TT - 1) % 3;
    const u64* tagb = tagsE + ((size_t)fs * NBB + bb) * TSTR;
    if (tid < NTAG) spin_tag(tagb + tid, (unsigned)(TT - 1));
    __syncthreads();
    const u64* ain = (const u64*)(bufB + (size_t)fs * BUFN) + (size_t)bb * TOTQ;
#pragma unroll
    for (int j = 0; j < NLD; ++j) {
      int g = tid + j * CBLK;
      atomicAdd(&srowF[g / RQ], sum4bf(ald8(ain + g)));
    }
    if (tid < NREM) {
      int g = tid + NLD * CBLK;
      atomicAdd(&srowF[g / RQ], sum4bf(ald8(ain + g)));
    }
    __syncthreads();
    if (wv == 0 && lrow == 0) out[bb * MB + lcol] = ll + logf(srowF[lcol]);
  }
}

extern "C" void kernel_launch(void* const* d_in, const int* in_sizes, int n_in,
                              void* d_out, int out_size, void* d_ws, size_t ws_size,
                              hipStream_t stream) {
  const int* seq = (const int*)d_in[0];
  const float* Al = (const float*)d_in[1];
  const float* Bl = (const float*)d_in[2];
  const float* il = (const float*)d_in[3];
  float* out = (float*)d_out;

  char* ws = (char*)d_ws;
  unsigned short* At = (unsigned short*)ws;               // 1040*1056*2 = 2,196,480
  size_t off_bt = (size_t)NP * KP * 2;
  float* Bt = (float*)(ws + off_bt);                      // 26*1040*4 = 108,160
  size_t off_ip = off_bt + (size_t)SS * BTS * 4;
  float* ip = (float*)(ws + off_ip);                      // 1040*4
  size_t off_buf = off_ip + (size_t)NP * 4;
  unsigned short* bufB = (unsigned short*)(ws + off_buf); // 3*256*1056*2 = 1,622,016
  size_t off_tag = off_buf + (size_t)3 * BUFN * 2;
  u64* tagsE = (u64*)(ws + off_tag);                      // 3*16*80*8 = 30,720
  size_t total = off_tag + (size_t)3 * NBB * TSTR * 8;
  int n16 = (int)((total + 15) / 16);

  k_zero<<<(n16 + 255) / 256, 256, 0, stream>>>((u32x4*)ws, n16);
  k_prep_init<<<1, 1024, 0, stream>>>(il, ip);
  k_prep_B<<<(QQ + 255) / 256, 256, 0, stream>>>(Bl, Bt);
  k_prep_A<<<QQ, 256, 0, stream>>>(Al, At);
  k_init_step<<<NB, 256, 0, stream>>>(seq, ip, Bt, bufB);

  void* args[] = {(void*)&seq, (void*)&At, (void*)&Bt, (void*)&bufB,
                  (void*)&tagsE, (void*)&out};
  hipLaunchCooperativeKernel((void*)k_hmm_coop, dim3(NBB * NSL), dim3(CBLK),
                             args, 0, stream);
}